// Round 13
// baseline (122.606 us; speedup 1.0000x reference)
//
#include <hip/hip_runtime.h>
#include <hip/hip_bf16.h>

#define NN 768
#define LL 8
#define HH 64
#define IT 16     // attn i-tile
#define SCP 772   // fp32 score row stride (words)
#define ABP 776   // bf16 alpha row stride (shorts); 1552 B, 16B-aligned

typedef __attribute__((ext_vector_type(8))) short bf16x8;
typedef __attribute__((ext_vector_type(4))) float f32x4;

__device__ __forceinline__ short f2bf(float x) {
    union { __hip_bfloat16 h; short s; } u;
    u.h = __float2bfloat16(x);
    return u.s;
}

// One 64x64 layer for a wave-private 2-row tile, 4-way k-split across lane
// bits 4-5. All lanes end with the full sum (xor-reduce); bias+relu applied.
__device__ __forceinline__ void layer2r(const float (*IN)[68], int k0, int c4,
                                        const float* __restrict__ W,
                                        const float* __restrict__ b,
                                        float4 res[2]) {
    float4 acc[2] = {{0,0,0,0},{0,0,0,0}};
    #pragma unroll
    for (int kk = 0; kk < 16; ++kk) {
        const int k = k0 + kk;
        const float4 wv = *(const float4*)&W[k * 64 + c4];
        #pragma unroll
        for (int rr = 0; rr < 2; ++rr) {
            const float xv = IN[rr][k];
            acc[rr].x = fmaf(xv, wv.x, acc[rr].x);
            acc[rr].y = fmaf(xv, wv.y, acc[rr].y);
            acc[rr].z = fmaf(xv, wv.z, acc[rr].z);
            acc[rr].w = fmaf(xv, wv.w, acc[rr].w);
        }
    }
    const float4 bb = *(const float4*)&b[c4];
    #pragma unroll
    for (int rr = 0; rr < 2; ++rr) {
        acc[rr].x += __shfl_xor(acc[rr].x, 16, 64);
        acc[rr].x += __shfl_xor(acc[rr].x, 32, 64);
        acc[rr].y += __shfl_xor(acc[rr].y, 16, 64);
        acc[rr].y += __shfl_xor(acc[rr].y, 32, 64);
        acc[rr].z += __shfl_xor(acc[rr].z, 16, 64);
        acc[rr].z += __shfl_xor(acc[rr].z, 32, 64);
        acc[rr].w += __shfl_xor(acc[rr].w, 16, 64);
        acc[rr].w += __shfl_xor(acc[rr].w, 32, 64);
        res[rr].x = fmaxf(acc[rr].x + bb.x, 0.f);
        res[rr].y = fmaxf(acc[rr].y + bb.y, 0.f);
        res[rr].z = fmaxf(acc[rr].z + bb.z, 0.f);
        res[rr].w = fmaxf(acc[rr].w + bb.w, 0.f);
    }
}

// Kernel 1 v7: 2-row wave-tasks. 3072 groups x 3 chains = 9216 waves in 2304
// blocks -> up to 8 waves/SIMD. All LDS wave-private, no __syncthreads.
__global__ __launch_bounds__(256) void qkv_kernel(
    const float* __restrict__ h, const float* __restrict__ coord,
    const float* __restrict__ wq1, const float* __restrict__ bq1,
    const float* __restrict__ wq2, const float* __restrict__ bq2,
    const float* __restrict__ wk1, const float* __restrict__ bk1,
    const float* __restrict__ wk2, const float* __restrict__ bk2,
    const float* __restrict__ wv1, const float* __restrict__ bv1,
    const float* __restrict__ wv2, const float* __restrict__ bv2,
    const float* __restrict__ wc1, const float* __restrict__ bc1,
    const float* __restrict__ wc2,
    short* __restrict__ q_ws, short* __restrict__ k_ws,
    short* __restrict__ vT_ws, short* __restrict__ UT_ws)
{
    const int lane  = threadIdx.x & 63;
    const int w     = threadIdx.x >> 6;
    const int wid   = blockIdx.x * 4 + w;
    const int chain = wid / 3072;          // 0..2
    const int rg    = wid - chain * 3072;  // 2-row group
    const int r0    = rg * 2;

    const int c4   = (lane & 15) * 4;
    const int ks   = (lane >> 4) & 3;
    const int k0   = ks * 16;
    const bool lead = (ks == 0);

    __shared__ float As[4][2][68];
    __shared__ float Bs[4][2][68];
    float (*A)[68] = As[w];
    float (*B)[68] = Bs[w];

    {
        const int row = lane >> 5;          // 0..1
        const int c2  = (lane & 31) * 2;    // 0..62
        *(float2*)&A[row][c2] = *(const float2*)&h[(r0 + row) * 64 + c2];
    }
    __builtin_amdgcn_wave_barrier();

    float4 res[2];

    if (chain == 0) {
        layer2r(A, k0, c4, wq1, bq1, res);
        if (lead) {
            *(float4*)&B[0][c4] = res[0];
            *(float4*)&B[1][c4] = res[1];
        }
        __builtin_amdgcn_wave_barrier();
        layer2r(B, k0, c4, wq2, bq2, res);
        if (lead) {
            #pragma unroll
            for (int rr = 0; rr < 2; ++rr) {
                const int g = r0 + rr, i = g >> 3, l = g & 7;
                short4 s;
                s.x = f2bf(res[rr].x); s.y = f2bf(res[rr].y);
                s.z = f2bf(res[rr].z); s.w = f2bf(res[rr].w);
                *(short4*)&q_ws[(l * NN + i) * 64 + c4] = s;
            }
        }
    } else if (chain == 1) {
        layer2r(A, k0, c4, wk1, bk1, res);
        if (lead) {
            *(float4*)&B[0][c4] = res[0];
            *(float4*)&B[1][c4] = res[1];
        }
        __builtin_amdgcn_wave_barrier();
        layer2r(B, k0, c4, wk2, bk2, res);
        if (lead) {
            #pragma unroll
            for (int rr = 0; rr < 2; ++rr) {
                const int g = r0 + rr, i = g >> 3, l = g & 7;
                short4 s;
                s.x = f2bf(res[rr].x); s.y = f2bf(res[rr].y);
                s.z = f2bf(res[rr].z); s.w = f2bf(res[rr].w);
                *(short4*)&k_ws[(l * NN + i) * 64 + c4] = s;
            }
        }
    } else {
        layer2r(A, k0, c4, wv1, bv1, res);
        if (lead) {
            *(float4*)&B[0][c4] = res[0];
            *(float4*)&B[1][c4] = res[1];
        }
        __builtin_amdgcn_wave_barrier();
        layer2r(B, k0, c4, wv2, bv2, res);
        if (lead) {
            #pragma unroll
            for (int rr = 0; rr < 2; ++rr) {
                const int g = r0 + rr, i = g >> 3, l = g & 7;
                vT_ws[((size_t)l * 64 + c4 + 0) * NN + i] = f2bf(res[rr].x);
                vT_ws[((size_t)l * 64 + c4 + 1) * NN + i] = f2bf(res[rr].y);
                vT_ws[((size_t)l * 64 + c4 + 2) * NN + i] = f2bf(res[rr].z);
                vT_ws[((size_t)l * 64 + c4 + 3) * NN + i] = f2bf(res[rr].w);
                *(float4*)&A[rr][c4] = res[rr];   // A now holds v (fp32)
            }
        }
        __builtin_amdgcn_wave_barrier();
        layer2r(A, k0, c4, wc1, bc1, res);
        if (lead) {
            *(float4*)&B[0][c4] = res[0];
            *(float4*)&B[1][c4] = res[1];
        }
        __builtin_amdgcn_wave_barrier();
        {
            const int row = lane >> 5;        // 0..1
            const int rem = lane & 31;
            const int kk  = rem >> 3;         // 0..3 coord channel
            const int seg = rem & 7;          // 0..7, 8-wide k segment
            float p = 0.f;
            #pragma unroll
            for (int k2 = 0; k2 < 8; ++k2) {
                const int k = seg * 8 + k2;
                p = fmaf(B[row][k], wc2[k * 4 + kk], p);
            }
            p += __shfl_xor(p, 1, 64);
            p += __shfl_xor(p, 2, 64);
            p += __shfl_xor(p, 4, 64);        // all 8 seg lanes hold cmv
            if (seg < 4) {
                const int g = r0 + row, i = g >> 3, l = g & 7;
                const float uval =
                    (seg == 0) ? p : p * coord[g * 12 + kk * 3 + (seg - 1)];
                UT_ws[((size_t)l * 16 + kk * 4 + seg) * NN + i] = f2bf(uval);
            }
        }
    }
}

// Kernel 2 v6 (MFMA, bf16 staging, vectorized softmax, dual-acc phase 2).
__global__ __launch_bounds__(256) void attn_kernel(
    const short* __restrict__ q_ws, const short* __restrict__ k_ws,
    const short* __restrict__ vT_ws, const short* __restrict__ UT_ws,
    const float* __restrict__ h, const float* __restrict__ coord,
    float* __restrict__ h_out, float* __restrict__ x_out)
{
    const int l    = blockIdx.x & 7;
    const int i0   = (blockIdx.x >> 3) * IT;
    const int t    = threadIdx.x;
    const int lane = t & 63;
    const int w    = t >> 6;
    const int m    = lane & 15;
    const int quad = lane >> 4;

    __shared__ float sc[IT][SCP];
    __shared__ alignas(16) short al[IT][ABP];
    __shared__ float rinv_s[IT];
    __shared__ float part3[4][IT][16];
    __shared__ float smS[IT][16];

    const bf16x8 aq0 = *(const bf16x8*)&q_ws[((size_t)l * NN + i0 + m) * 64 + quad * 8];
    const bf16x8 aq1 = *(const bf16x8*)&q_ws[((size_t)l * NN + i0 + m) * 64 + 32 + quad * 8];

    // ---- Phase 1: scores; wave w covers j in [192w, 192w+192)
    {
        const short* kl = k_ws + (size_t)l * NN * 64;
        for (int nt = 0; nt < 12; ++nt) {
            const int jb = 192 * w + nt * 16;
            const short* krow = kl + (size_t)(jb + m) * 64;
            bf16x8 b0 = *(const bf16x8*)(krow + quad * 8);
            bf16x8 b1 = *(const bf16x8*)(krow + 32 + quad * 8);
            f32x4 d = {0.f, 0.f, 0.f, 0.f};
            d = __builtin_amdgcn_mfma_f32_16x16x32_bf16(aq0, b0, d, 0, 0, 0);
            d = __builtin_amdgcn_mfma_f32_16x16x32_bf16(aq1, b1, d, 0, 0, 0);
            #pragma unroll
            for (int rg = 0; rg < 4; ++rg)
                sc[quad * 4 + rg][jb + m] = d[rg];
        }
    }
    __syncthreads();

    // ---- softmax (vectorized comb ownership)
    {
        const int r = t >> 4, sub = t & 15;
        float4 v[12];
        #pragma unroll
        for (int jj = 0; jj < 12; ++jj)
            v[jj] = *(const float4*)&sc[r][sub * 4 + 64 * jj];
        float mx = -1e30f;
        #pragma unroll
        for (int jj = 0; jj < 12; ++jj)
            mx = fmaxf(mx, fmaxf(fmaxf(v[jj].x, v[jj].y),
                                 fmaxf(v[jj].z, v[jj].w)));
        mx = fmaxf(mx, __shfl_xor(mx, 1, 64));
        mx = fmaxf(mx, __shfl_xor(mx, 2, 64));
        mx = fmaxf(mx, __shfl_xor(mx, 4, 64));
        mx = fmaxf(mx, __shfl_xor(mx, 8, 64));
        float s = 0.f;
        #pragma unroll
        for (int jj = 0; jj < 12; ++jj) {
            const float e0 = __expf(v[jj].x - mx);
            const float e1 = __expf(v[jj].y - mx);
            const float e2 = __expf(v[jj].z - mx);
            const float e3 = __expf(v[jj].w - mx);
            s += (e0 + e1) + (e2 + e3);
            short4 p;
            p.x = f2bf(e0); p.y = f2bf(e1); p.z = f2bf(e2); p.w = f2bf(e3);
            *(short4*)&al[r][sub * 4 + 64 * jj] = p;
        }
        s += __shfl_xor(s, 1, 64);
        s += __shfl_xor(s, 2, 64);
        s += __shfl_xor(s, 4, 64);
        s += __shfl_xor(s, 8, 64);
        if (sub == 0) rinv_s[r] = 1.f / s;
    }
    __syncthreads();

    // ---- Phase 2: h_agg = alpha @ v; dual accumulators break the MFMA chain
    {
        f32x4 acc0 = {0.f, 0.f, 0.f, 0.f};
        f32x4 acc1 = {0.f, 0.f, 0.f, 0.f};
        const short* vrow = vT_ws + ((size_t)l * 64 + 16 * w + m) * NN;
        #pragma unroll 4
        for (int kt = 0; kt < 24; kt += 2) {
            const int ka = kt * 32, kb = ka + 32;
            bf16x8 a0 = *(const bf16x8*)&al[m][ka + quad * 8];
            bf16x8 b0 = *(const bf16x8*)(vrow + ka + quad * 8);
            bf16x8 a1 = *(const bf16x8*)&al[m][kb + quad * 8];
            bf16x8 b1 = *(const bf16x8*)(vrow + kb + quad * 8);
            acc0 = __builtin_amdgcn_mfma_f32_16x16x32_bf16(a0, b0, acc0, 0, 0, 0);
            acc1 = __builtin_amdgcn_mfma_f32_16x16x32_bf16(a1, b1, acc1, 0, 0, 0);
        }
        const int c = 16 * w + m;
        #pragma unroll
        for (int rg = 0; rg < 4; ++rg) {
            const int i = quad * 4 + rg;
            const int row = ((i0 + i) * 8 + l) * 64 + c;
            h_out[row] = h[row] + rinv_s[i] * (acc0[rg] + acc1[rg]);
        }
    }

    // ---- Phase 3: S = alpha @ U, 4-way K-split across waves
    {
        f32x4 acc = {0.f, 0.f, 0.f, 0.f};
        const short* urow = UT_ws + ((size_t)l * 16 + m) * NN + 192 * w;
        #pragma unroll
        for (int kt = 0; kt < 6; ++kt) {
            const int k0 = kt * 32;
            bf16x8 a = *(const bf16x8*)&al[m][192 * w + k0 + quad * 8];
            bf16x8 b = *(const bf16x8*)(urow + k0 + quad * 8);
            acc = __builtin_amdgcn_mfma_f32_16x16x32_bf16(a, b, acc, 0, 0, 0);
        }
        #pragma unroll
        for (int rg = 0; rg < 4; ++rg)
            part3[w][quad * 4 + rg][m] = acc[rg];
    }
    __syncthreads();
    {
        const int i = t >> 4, u = t & 15;
        smS[i][u] = (part3[0][i][u] + part3[1][i][u] +
                     part3[2][i][u] + part3[3][i][u]) * rinv_s[i];
    }
    __syncthreads();
    if (t < 192) {
        const int i4 = t / 12, kt = t % 12, k4 = kt / 3, s4 = kt % 3;
        const int idx = ((i0 + i4) * 8 + l) * 12 + kt;
        const float cd = coord[idx];
        x_out[idx] = cd + cd * smS[i4][k4 * 4] - smS[i4][k4 * 4 + 1 + s4];
    }
}

extern "C" void kernel_launch(void* const* d_in, const int* in_sizes, int n_in,
                              void* d_out, int out_size, void* d_ws, size_t ws_size,
                              hipStream_t stream) {
    const float* h     = (const float*)d_in[0];
    const float* coord = (const float*)d_in[1];

    float* h_out = (float*)d_out;
    float* x_out = h_out + NN * LL * HH;     // 393216 floats

    short* q_ws  = (short*)d_ws;             // [L][N][64] bf16
    short* k_ws  = q_ws + NN * LL * HH;      // [L][N][64] bf16
    short* vT_ws = k_ws + NN * LL * HH;      // [L][64][N] bf16
    short* UT_ws = vT_ws + NN * LL * HH;     // [L][16][N] bf16

    qkv_kernel<<<2304, 256, 0, stream>>>(
        h, coord,
        (const float*)d_in[2],  (const float*)d_in[3],
        (const float*)d_in[4],  (const float*)d_in[5],
        (const float*)d_in[6],  (const float*)d_in[7],
        (const float*)d_in[8],  (const float*)d_in[9],
        (const float*)d_in[10], (const float*)d_in[11],
        (const float*)d_in[12], (const float*)d_in[13],
        (const float*)d_in[14], (const float*)d_in[15],
        (const float*)d_in[16],
        q_ws, k_ws, vT_ws, UT_ws);

    attn_kernel<<<(NN / IT) * LL, 256, 0, stream>>>(
        q_ws, k_ws, vT_ws, UT_ws, h, coord, h_out, x_out);
}

// Round 15
// 114.799 us; speedup vs baseline: 1.0680x; 1.0680x over previous
//
#include <hip/hip_runtime.h>
#include <hip/hip_bf16.h>

#define NN 768
#define LL 8
#define HH 64
#define IT 16     // attn i-tile
#define SCP 772   // fp32 score row stride (words)
#define ABP 776   // bf16 alpha row stride (shorts); 1552 B, 16B-aligned
#define XST 80    // qkv LDS X-tile row stride in shorts (160 B, 16B-aligned)

typedef __attribute__((ext_vector_type(8))) short bf16x8;
typedef __attribute__((ext_vector_type(4))) float f32x4;

__device__ __forceinline__ short f2bf(float x) {
    union { __hip_bfloat16 h; short s; } u;
    u.h = __float2bfloat16(x);
    return u.s;
}

__device__ __forceinline__ bf16x8 pack8(float4 lo, float4 hi) {
    bf16x8 r;
    r[0] = f2bf(lo.x); r[1] = f2bf(lo.y); r[2] = f2bf(lo.z); r[3] = f2bf(lo.w);
    r[4] = f2bf(hi.x); r[5] = f2bf(hi.y); r[6] = f2bf(hi.z); r[7] = f2bf(hi.w);
    return r;
}

// ---- Kernel 0: transpose+convert weights to bf16 n-major WT[n*64+k]=W[k*64+n].
// 7 full 64x64 (wq1,wq2,wk1,wk2,wv1,wv2,wc1) + wc2 zero-padded to 16x64.
__global__ __launch_bounds__(256) void prep_kernel(
    const float* __restrict__ wq1, const float* __restrict__ wq2,
    const float* __restrict__ wk1, const float* __restrict__ wk2,
    const float* __restrict__ wv1, const float* __restrict__ wv2,
    const float* __restrict__ wc1, const float* __restrict__ wc2,
    short* __restrict__ WT)
{
    const int idx = blockIdx.x * 256 + threadIdx.x;   // 0..29695
    if (idx < 28672) {
        const int mm = idx >> 12, rem = idx & 4095;
        const int n = rem >> 6, kk = rem & 63;
        const float* srcs[7] = {wq1, wq2, wk1, wk2, wv1, wv2, wc1};
        WT[idx] = f2bf(srcs[mm][kk * 64 + n]);
    } else if (idx < 29696) {
        const int rem = idx - 28672;
        const int n = rem >> 6, kk = rem & 63;
        WT[idx] = (n < 4) ? f2bf(wc2[kk * 4 + n]) : (short)0;
    }
}

// One 64->64 MFMA layer for a 16-row tile held by ONE wave.
// a0/a1: A-frags (rows m=lane&15, K halves). WT: bf16 n-major weights.
// dout[nt]: D for col-tile nt (cols nt*16 + (lane&15)), rows quad*4+rg.
__device__ __forceinline__ void layer_mfma(bf16x8 a0, bf16x8 a1,
                                           const short* __restrict__ WT,
                                           const float* __restrict__ bias,
                                           int m, int quad, bool do_relu,
                                           f32x4 dout[4])
{
    #pragma unroll
    for (int nt = 0; nt < 4; ++nt) {
        const short* wp = WT + (nt * 16 + m) * 64 + quad * 8;
        bf16x8 b0 = *(const bf16x8*)wp;
        bf16x8 b1 = *(const bf16x8*)(wp + 32);
        f32x4 d = {0.f, 0.f, 0.f, 0.f};
        d = __builtin_amdgcn_mfma_f32_16x16x32_bf16(a0, b0, d, 0, 0, 0);
        d = __builtin_amdgcn_mfma_f32_16x16x32_bf16(a1, b1, d, 0, 0, 0);
        if (bias) {
            const float bb = bias[nt * 16 + m];
            #pragma unroll
            for (int rg = 0; rg < 4; ++rg) d[rg] += bb;
        }
        if (do_relu) {
            #pragma unroll
            for (int rg = 0; rg < 4; ++rg) d[rg] = fmaxf(d[rg], 0.f);
        }
        dout[nt] = d;
    }
}

// store D tile (C-layout) into the wave-private LDS X tile, row-major bf16
__device__ __forceinline__ void d_to_X(const f32x4 d[4], short (*X)[XST],
                                       int m, int quad) {
    #pragma unroll
    for (int nt = 0; nt < 4; ++nt)
        #pragma unroll
        for (int rg = 0; rg < 4; ++rg)
            X[quad * 4 + rg][nt * 16 + m] = f2bf(d[nt][rg]);
}

// Kernel 1 v8 (MFMA MLPs): wave-task = (16-row tile, chain). 384 tiles x 3
// chains = 1152 waves in 288 blocks. Wave-private LDS, no __syncthreads.
__global__ __launch_bounds__(256) void qkv_kernel(
    const float* __restrict__ h, const float* __restrict__ coord,
    const float* __restrict__ bq1, const float* __restrict__ bq2,
    const float* __restrict__ bk1, const float* __restrict__ bk2,
    const float* __restrict__ bv1, const float* __restrict__ bv2,
    const float* __restrict__ bc1,
    const short* __restrict__ WT,
    short* __restrict__ q_ws, short* __restrict__ k_ws,
    short* __restrict__ vT_ws, short* __restrict__ UT_ws)
{
    const int lane = threadIdx.x & 63;
    const int w    = threadIdx.x >> 6;
    const int wid  = blockIdx.x * 4 + w;
    const int chain = wid / 384;           // 0=q 1=k 2=v+cmv
    const int rt    = wid - chain * 384;   // 16-row tile
    const int r0    = rt * 16;

    const int m    = lane & 15;
    const int quad = lane >> 4;

    __shared__ short Xs[4][16][XST];
    __shared__ float cms[4][16][4];
    short (*X)[XST] = Xs[w];

    const short* WT_q1 = WT;
    const short* WT_q2 = WT + 4096;
    const short* WT_k1 = WT + 8192;
    const short* WT_k2 = WT + 12288;
    const short* WT_v1 = WT + 16384;
    const short* WT_v2 = WT + 20480;
    const short* WT_c1 = WT + 24576;
    const short* WT_c2 = WT + 28672;

    // layer-1 A-frags straight from global h (fp32 -> bf16)
    bf16x8 a0, a1;
    {
        const float* hrow = h + (size_t)(r0 + m) * 64;
        a0 = pack8(*(const float4*)(hrow + quad * 8),
                   *(const float4*)(hrow + quad * 8 + 4));
        a1 = pack8(*(const float4*)(hrow + 32 + quad * 8),
                   *(const float4*)(hrow + 32 + quad * 8 + 4));
    }

    f32x4 d[4];

    if (chain == 0) {
        layer_mfma(a0, a1, WT_q1, bq1, m, quad, true, d);
        d_to_X(d, X, m, quad);
        __builtin_amdgcn_wave_barrier();
        a0 = *(const bf16x8*)&X[m][quad * 8];
        a1 = *(const bf16x8*)&X[m][32 + quad * 8];
        layer_mfma(a0, a1, WT_q2, bq2, m, quad, true, d);
        #pragma unroll
        for (int nt = 0; nt < 4; ++nt)
            #pragma unroll
            for (int rg = 0; rg < 4; ++rg) {
                const int g = r0 + quad * 4 + rg, i = g >> 3, l = g & 7;
                q_ws[(l * NN + i) * 64 + nt * 16 + m] = f2bf(d[nt][rg]);
            }
    } else if (chain == 1) {
        layer_mfma(a0, a1, WT_k1, bk1, m, quad, true, d);
        d_to_X(d, X, m, quad);
        __builtin_amdgcn_wave_barrier();
        a0 = *(const bf16x8*)&X[m][quad * 8];
        a1 = *(const bf16x8*)&X[m][32 + quad * 8];
        layer_mfma(a0, a1, WT_k2, bk2, m, quad, true, d);
        #pragma unroll
        for (int nt = 0; nt < 4; ++nt)
            #pragma unroll
            for (int rg = 0; rg < 4; ++rg) {
                const int g = r0 + quad * 4 + rg, i = g >> 3, l = g & 7;
                k_ws[(l * NN + i) * 64 + nt * 16 + m] = f2bf(d[nt][rg]);
            }
    } else {
        layer_mfma(a0, a1, WT_v1, bv1, m, quad, true, d);
        d_to_X(d, X, m, quad);
        __builtin_amdgcn_wave_barrier();
        a0 = *(const bf16x8*)&X[m][quad * 8];
        a1 = *(const bf16x8*)&X[m][32 + quad * 8];
        layer_mfma(a0, a1, WT_v2, bv2, m, quad, true, d);
        // v: transposed scalar stores + X (input to coord_mlp)
        #pragma unroll
        for (int nt = 0; nt < 4; ++nt)
            #pragma unroll
            for (int rg = 0; rg < 4; ++rg) {
                const int g = r0 + quad * 4 + rg, i = g >> 3, l = g & 7;
                vT_ws[((size_t)l * 64 + nt * 16 + m) * NN + i] = f2bf(d[nt][rg]);
            }
        d_to_X(d, X, m, quad);
        __builtin_amdgcn_wave_barrier();
        a0 = *(const bf16x8*)&X[m][quad * 8];
        a1 = *(const bf16x8*)&X[m][32 + quad * 8];
        layer_mfma(a0, a1, WT_c1, bc1, m, quad, true, d);
        d_to_X(d, X, m, quad);
        __builtin_amdgcn_wave_barrier();
        a0 = *(const bf16x8*)&X[m][quad * 8];
        a1 = *(const bf16x8*)&X[m][32 + quad * 8];
        // cmv = t1 @ wc2 (no bias, no relu); only cols 0..3 meaningful
        {
            const short* wp = WT_c2 + m * 64 + quad * 8;
            bf16x8 b0 = *(const bf16x8*)wp;
            bf16x8 b1 = *(const bf16x8*)(wp + 32);
            f32x4 dc = {0.f, 0.f, 0.f, 0.f};
            dc = __builtin_amdgcn_mfma_f32_16x16x32_bf16(a0, b0, dc, 0, 0, 0);
            dc = __builtin_amdgcn_mfma_f32_16x16x32_bf16(a1, b1, dc, 0, 0, 0);
            if (m < 4) {
                #pragma unroll
                for (int rg = 0; rg < 4; ++rg)
                    cms[w][quad * 4 + rg][m] = dc[rg];
            }
        }
        __builtin_amdgcn_wave_barrier();
        // U build: lane -> (row = lane>>2, kk = lane&3), 4 seg outputs
        {
            const int row = lane >> 2, kk = lane & 3;
            const float c = cms[w][row][kk];
            const int g = r0 + row, i = g >> 3, l = g & 7;
            UT_ws[((size_t)l * 16 + kk * 4 + 0) * NN + i] = f2bf(c);
            #pragma unroll
            for (int seg = 1; seg < 4; ++seg) {
                const float uval = c * coord[g * 12 + kk * 3 + (seg - 1)];
                UT_ws[((size_t)l * 16 + kk * 4 + seg) * NN + i] = f2bf(uval);
            }
        }
    }
}

// Kernel 2 v6 (frozen from R13: MFMA, vectorized softmax, dual-acc phase 2).
__global__ __launch_bounds__(256) void attn_kernel(
    const short* __restrict__ q_ws, const short* __restrict__ k_ws,
    const short* __restrict__ vT_ws, const short* __restrict__ UT_ws,
    const float* __restrict__ h, const float* __restrict__ coord,
    float* __restrict__ h_out, float* __restrict__ x_out)
{
    const int l    = blockIdx.x & 7;
    const int i0   = (blockIdx.x >> 3) * IT;
    const int t    = threadIdx.x;
    const int lane = t & 63;
    const int w    = t >> 6;
    const int m    = lane & 15;
    const int quad = lane >> 4;

    __shared__ float sc[IT][SCP];
    __shared__ alignas(16) short al[IT][ABP];
    __shared__ float rinv_s[IT];
    __shared__ float part3[4][IT][16];
    __shared__ float smS[IT][16];

    const bf16x8 aq0 = *(const bf16x8*)&q_ws[((size_t)l * NN + i0 + m) * 64 + quad * 8];
    const bf16x8 aq1 = *(const bf16x8*)&q_ws[((size_t)l * NN + i0 + m) * 64 + 32 + quad * 8];

    {
        const short* kl = k_ws + (size_t)l * NN * 64;
        for (int nt = 0; nt < 12; ++nt) {
            const int jb = 192 * w + nt * 16;
            const short* krow = kl + (size_t)(jb + m) * 64;
            bf16x8 b0 = *(const bf16x8*)(krow + quad * 8);
            bf16x8 b1 = *(const bf16x8*)(krow + 32 + quad * 8);
            f32x4 d = {0.f, 0.f, 0.f, 0.f};
            d = __builtin_amdgcn_mfma_f32_16x16x32_bf16(aq0, b0, d, 0, 0, 0);
            d = __builtin_amdgcn_mfma_f32_16x16x32_bf16(aq1, b1, d, 0, 0, 0);
            #pragma unroll
            for (int rg = 0; rg < 4; ++rg)
                sc[quad * 4 + rg][jb + m] = d[rg];
        }
    }
    __syncthreads();

    {
        const int r = t >> 4, sub = t & 15;
        float4 v[12];
        #pragma unroll
        for (int jj = 0; jj < 12; ++jj)
            v[jj] = *(const float4*)&sc[r][sub * 4 + 64 * jj];
        float mx = -1e30f;
        #pragma unroll
        for (int jj = 0; jj < 12; ++jj)
            mx = fmaxf(mx, fmaxf(fmaxf(v[jj].x, v[jj].y),
                                 fmaxf(v[jj].z, v[jj].w)));
        mx = fmaxf(mx, __shfl_xor(mx, 1, 64));
        mx = fmaxf(mx, __shfl_xor(mx, 2, 64));
        mx = fmaxf(mx, __shfl_xor(mx, 4, 64));
        mx = fmaxf(mx, __shfl_xor(mx, 8, 64));
        float s = 0.f;
        #pragma unroll
        for (int jj = 0; jj < 12; ++jj) {
            const float e0 = __expf(v[jj].x - mx);
            const float e1 = __expf(v[jj].y - mx);
            const float e2 = __expf(v[jj].z - mx);
            const float e3 = __expf(v[jj].w - mx);
            s += (e0 + e1) + (e2 + e3);
            short4 p;
            p.x = f2bf(e0); p.y = f2bf(e1); p.z = f2bf(e2); p.w = f2bf(e3);
            *(short4*)&al[r][sub * 4 + 64 * jj] = p;
        }
        s += __shfl_xor(s, 1, 64);
        s += __shfl_xor(s, 2, 64);
        s += __shfl_xor(s, 4, 64);
        s += __shfl_xor(s, 8, 64);
        if (sub == 0) rinv_s[r] = 1.f / s;
    }
    __syncthreads();

    {
        f32x4 acc0 = {0.f, 0.f, 0.f, 0.f};
        f32x4 acc1 = {0.f, 0.f, 0.f, 0.f};
        const short* vrow = vT_ws + ((size_t)l * 64 + 16 * w + m) * NN;
        #pragma unroll 4
        for (int kt = 0; kt < 24; kt += 2) {
            const int ka = kt * 32, kb = ka + 32;
            bf16x8 a0 = *(const bf16x8*)&al[m][ka + quad * 8];
            bf16x8 b0 = *(const bf16x8*)(vrow + ka + quad * 8);
            bf16x8 a1 = *(const bf16x8*)&al[m][kb + quad * 8];
            bf16x8 b1 = *(const bf16x8*)(vrow + kb + quad * 8);
            acc0 = __builtin_amdgcn_mfma_f32_16x16x32_bf16(a0, b0, acc0, 0, 0, 0);
            acc1 = __builtin_amdgcn_mfma_f32_16x16x32_bf16(a1, b1, acc1, 0, 0, 0);
        }
        const int c = 16 * w + m;
        #pragma unroll
        for (int rg = 0; rg < 4; ++rg) {
            const int i = quad * 4 + rg;
            const int row = ((i0 + i) * 8 + l) * 64 + c;
            h_out[row] = h[row] + rinv_s[i] * (acc0[rg] + acc1[rg]);
        }
    }

    {
        f32x4 acc = {0.f, 0.f, 0.f, 0.f};
        const short* urow = UT_ws + ((size_t)l * 16 + m) * NN + 192 * w;
        #pragma unroll
        for (int kt = 0; kt < 6; ++kt) {
            const int k0 = kt * 32;
            bf16x8 a = *(const bf16x8*)&al[m][192 * w + k0 + quad * 8];
            bf16x8 b = *(const bf16x8*)(urow + k0 + quad * 8);
            acc = __builtin_amdgcn_mfma_f32_16x16x32_bf16(a, b, acc, 0, 0, 0);
        }
        #pragma unroll
        for (int rg = 0; rg < 4; ++rg)
            part3[w][quad * 4 + rg][m] = acc[rg];
    }
    __syncthreads();
    {
        const int i = t >> 4, u = t & 15;
        smS[i][u] = (part3[0][i][u] + part3[1][i][u] +
                     part3[2][i][u] + part3[3][i][u]) * rinv_s[i];
    }
    __syncthreads();
    if (t < 192) {
        const int i4 = t / 12, kt = t % 12, k4 = kt / 3, s4 = kt % 3;
        const int idx = ((i0 + i4) * 8 + l) * 12 + kt;
        const float cd = coord[idx];
        x_out[idx] = cd + cd * smS[i4][k4 * 4] - smS[i4][k4 * 4 + 1 + s4];
    }
}

extern "C" void kernel_launch(void* const* d_in, const int* in_sizes, int n_in,
                              void* d_out, int out_size, void* d_ws, size_t ws_size,
                              hipStream_t stream) {
    const float* h     = (const float*)d_in[0];
    const float* coord = (const float*)d_in[1];

    float* h_out = (float*)d_out;
    float* x_out = h_out + NN * LL * HH;     // 393216 floats

    short* q_ws  = (short*)d_ws;             // [L][N][64] bf16
    short* k_ws  = q_ws + NN * LL * HH;      // [L][N][64] bf16
    short* vT_ws = k_ws + NN * LL * HH;      // [L][64][N] bf16
    short* UT_ws = vT_ws + NN * LL * HH;     // [L][16][N] bf16
    short* WT    = UT_ws + NN * LL * 16;     // 29696 shorts of bf16 weights

    prep_kernel<<<116, 256, 0, stream>>>(
        (const float*)d_in[2],  (const float*)d_in[4],
        (const float*)d_in[6],  (const float*)d_in[8],
        (const float*)d_in[10], (const float*)d_in[12],
        (const float*)d_in[14], (const float*)d_in[16], WT);

    qkv_kernel<<<288, 256, 0, stream>>>(
        h, coord,
        (const float*)d_in[3],  (const float*)d_in[5],
        (const float*)d_in[7],  (const float*)d_in[9],
        (const float*)d_in[11], (const float*)d_in[13],
        (const float*)d_in[15],
        WT, q_ws, k_ws, vT_ws, UT_ws);

    attn_kernel<<<(NN / IT) * LL, 256, 0, stream>>>(
        q_ws, k_ws, vT_ws, UT_ws, h, coord, h_out, x_out);
}

// Round 16
// 114.422 us; speedup vs baseline: 1.0715x; 1.0033x over previous
//
#include <hip/hip_runtime.h>
#include <hip/hip_bf16.h>

#define NN 768
#define LL 8
#define HH 64
#define IT 16     // attn i-tile
#define ABP 776   // bf16 alpha row stride (shorts); 1552 B, 16B-aligned
#define XST 80    // qkv LDS X-tile row stride in shorts (160 B, 16B-aligned)

typedef __attribute__((ext_vector_type(8))) short bf16x8;
typedef __attribute__((ext_vector_type(4))) float f32x4;

__device__ __forceinline__ short f2bf(float x) {
    union { __hip_bfloat16 h; short s; } u;
    u.h = __float2bfloat16(x);
    return u.s;
}

__device__ __forceinline__ bf16x8 pack8(float4 lo, float4 hi) {
    bf16x8 r;
    r[0] = f2bf(lo.x); r[1] = f2bf(lo.y); r[2] = f2bf(lo.z); r[3] = f2bf(lo.w);
    r[4] = f2bf(hi.x); r[5] = f2bf(hi.y); r[6] = f2bf(hi.z); r[7] = f2bf(hi.w);
    return r;
}

// ---- Kernel 0 (frozen): transpose+convert weights to bf16 n-major.
__global__ __launch_bounds__(256) void prep_kernel(
    const float* __restrict__ wq1, const float* __restrict__ wq2,
    const float* __restrict__ wk1, const float* __restrict__ wk2,
    const float* __restrict__ wv1, const float* __restrict__ wv2,
    const float* __restrict__ wc1, const float* __restrict__ wc2,
    short* __restrict__ WT)
{
    const int idx = blockIdx.x * 256 + threadIdx.x;   // 0..29695
    if (idx < 28672) {
        const int mm = idx >> 12, rem = idx & 4095;
        const int n = rem >> 6, kk = rem & 63;
        const float* srcs[7] = {wq1, wq2, wk1, wk2, wv1, wv2, wc1};
        WT[idx] = f2bf(srcs[mm][kk * 64 + n]);
    } else if (idx < 29696) {
        const int rem = idx - 28672;
        const int n = rem >> 6, kk = rem & 63;
        WT[idx] = (n < 4) ? f2bf(wc2[kk * 4 + n]) : (short)0;
    }
}

// One 64->64 MFMA layer for a 16-row tile held by ONE wave. (frozen)
__device__ __forceinline__ void layer_mfma(bf16x8 a0, bf16x8 a1,
                                           const short* __restrict__ WT,
                                           const float* __restrict__ bias,
                                           int m, int quad, bool do_relu,
                                           f32x4 dout[4])
{
    #pragma unroll
    for (int nt = 0; nt < 4; ++nt) {
        const short* wp = WT + (nt * 16 + m) * 64 + quad * 8;
        bf16x8 b0 = *(const bf16x8*)wp;
        bf16x8 b1 = *(const bf16x8*)(wp + 32);
        f32x4 d = {0.f, 0.f, 0.f, 0.f};
        d = __builtin_amdgcn_mfma_f32_16x16x32_bf16(a0, b0, d, 0, 0, 0);
        d = __builtin_amdgcn_mfma_f32_16x16x32_bf16(a1, b1, d, 0, 0, 0);
        if (bias) {
            const float bb = bias[nt * 16 + m];
            #pragma unroll
            for (int rg = 0; rg < 4; ++rg) d[rg] += bb;
        }
        if (do_relu) {
            #pragma unroll
            for (int rg = 0; rg < 4; ++rg) d[rg] = fmaxf(d[rg], 0.f);
        }
        dout[nt] = d;
    }
}

__device__ __forceinline__ void d_to_X(const f32x4 d[4], short (*X)[XST],
                                       int m, int quad) {
    #pragma unroll
    for (int nt = 0; nt < 4; ++nt)
        #pragma unroll
        for (int rg = 0; rg < 4; ++rg)
            X[quad * 4 + rg][nt * 16 + m] = f2bf(d[nt][rg]);
}

// Kernel 1 v8 (frozen): MFMA MLPs, wave-task = (16-row tile, chain).
__global__ __launch_bounds__(256) void qkv_kernel(
    const float* __restrict__ h, const float* __restrict__ coord,
    const float* __restrict__ bq1, const float* __restrict__ bq2,
    const float* __restrict__ bk1, const float* __restrict__ bk2,
    const float* __restrict__ bv1, const float* __restrict__ bv2,
    const float* __restrict__ bc1,
    const short* __restrict__ WT,
    short* __restrict__ q_ws, short* __restrict__ k_ws,
    short* __restrict__ vT_ws, short* __restrict__ UT_ws)
{
    const int lane = threadIdx.x & 63;
    const int w    = threadIdx.x >> 6;
    const int wid  = blockIdx.x * 4 + w;
    const int chain = wid / 384;
    const int rt    = wid - chain * 384;
    const int r0    = rt * 16;

    const int m    = lane & 15;
    const int quad = lane >> 4;

    __shared__ short Xs[4][16][XST];
    __shared__ float cms[4][16][4];
    short (*X)[XST] = Xs[w];

    const short* WT_q1 = WT;
    const short* WT_q2 = WT + 4096;
    const short* WT_k1 = WT + 8192;
    const short* WT_k2 = WT + 12288;
    const short* WT_v1 = WT + 16384;
    const short* WT_v2 = WT + 20480;
    const short* WT_c1 = WT + 24576;
    const short* WT_c2 = WT + 28672;

    bf16x8 a0, a1;
    {
        const float* hrow = h + (size_t)(r0 + m) * 64;
        a0 = pack8(*(const float4*)(hrow + quad * 8),
                   *(const float4*)(hrow + quad * 8 + 4));
        a1 = pack8(*(const float4*)(hrow + 32 + quad * 8),
                   *(const float4*)(hrow + 32 + quad * 8 + 4));
    }

    f32x4 d[4];

    if (chain == 0) {
        layer_mfma(a0, a1, WT_q1, bq1, m, quad, true, d);
        d_to_X(d, X, m, quad);
        __builtin_amdgcn_wave_barrier();
        a0 = *(const bf16x8*)&X[m][quad * 8];
        a1 = *(const bf16x8*)&X[m][32 + quad * 8];
        layer_mfma(a0, a1, WT_q2, bq2, m, quad, true, d);
        #pragma unroll
        for (int nt = 0; nt < 4; ++nt)
            #pragma unroll
            for (int rg = 0; rg < 4; ++rg) {
                const int g = r0 + quad * 4 + rg, i = g >> 3, l = g & 7;
                q_ws[(l * NN + i) * 64 + nt * 16 + m] = f2bf(d[nt][rg]);
            }
    } else if (chain == 1) {
        layer_mfma(a0, a1, WT_k1, bk1, m, quad, true, d);
        d_to_X(d, X, m, quad);
        __builtin_amdgcn_wave_barrier();
        a0 = *(const bf16x8*)&X[m][quad * 8];
        a1 = *(const bf16x8*)&X[m][32 + quad * 8];
        layer_mfma(a0, a1, WT_k2, bk2, m, quad, true, d);
        #pragma unroll
        for (int nt = 0; nt < 4; ++nt)
            #pragma unroll
            for (int rg = 0; rg < 4; ++rg) {
                const int g = r0 + quad * 4 + rg, i = g >> 3, l = g & 7;
                k_ws[(l * NN + i) * 64 + nt * 16 + m] = f2bf(d[nt][rg]);
            }
    } else {
        layer_mfma(a0, a1, WT_v1, bv1, m, quad, true, d);
        d_to_X(d, X, m, quad);
        __builtin_amdgcn_wave_barrier();
        a0 = *(const bf16x8*)&X[m][quad * 8];
        a1 = *(const bf16x8*)&X[m][32 + quad * 8];
        layer_mfma(a0, a1, WT_v2, bv2, m, quad, true, d);
        #pragma unroll
        for (int nt = 0; nt < 4; ++nt)
            #pragma unroll
            for (int rg = 0; rg < 4; ++rg) {
                const int g = r0 + quad * 4 + rg, i = g >> 3, l = g & 7;
                vT_ws[((size_t)l * 64 + nt * 16 + m) * NN + i] = f2bf(d[nt][rg]);
            }
        d_to_X(d, X, m, quad);
        __builtin_amdgcn_wave_barrier();
        a0 = *(const bf16x8*)&X[m][quad * 8];
        a1 = *(const bf16x8*)&X[m][32 + quad * 8];
        layer_mfma(a0, a1, WT_c1, bc1, m, quad, true, d);
        d_to_X(d, X, m, quad);
        __builtin_amdgcn_wave_barrier();
        a0 = *(const bf16x8*)&X[m][quad * 8];
        a1 = *(const bf16x8*)&X[m][32 + quad * 8];
        {
            const short* wp = WT_c2 + m * 64 + quad * 8;
            bf16x8 b0 = *(const bf16x8*)wp;
            bf16x8 b1 = *(const bf16x8*)(wp + 32);
            f32x4 dc = {0.f, 0.f, 0.f, 0.f};
            dc = __builtin_amdgcn_mfma_f32_16x16x32_bf16(a0, b0, dc, 0, 0, 0);
            dc = __builtin_amdgcn_mfma_f32_16x16x32_bf16(a1, b1, dc, 0, 0, 0);
            if (m < 4) {
                #pragma unroll
                for (int rg = 0; rg < 4; ++rg)
                    cms[w][quad * 4 + rg][m] = dc[rg];
            }
        }
        __builtin_amdgcn_wave_barrier();
        {
            const int row = lane >> 2, kk = lane & 3;
            const float c = cms[w][row][kk];
            const int g = r0 + row, i = g >> 3, l = g & 7;
            UT_ws[((size_t)l * 16 + kk * 4 + 0) * NN + i] = f2bf(c);
            #pragma unroll
            for (int seg = 1; seg < 4; ++seg) {
                const float uval = c * coord[g * 12 + kk * 3 + (seg - 1)];
                UT_ws[((size_t)l * 16 + kk * 4 + seg) * NN + i] = f2bf(uval);
            }
        }
    }
}

// Kernel 2 v7: register-resident scores. LDS 78KB -> ~31KB (5 blocks/CU).
__global__ __launch_bounds__(256) void attn_kernel(
    const short* __restrict__ q_ws, const short* __restrict__ k_ws,
    const short* __restrict__ vT_ws, const short* __restrict__ UT_ws,
    const float* __restrict__ h, const float* __restrict__ coord,
    float* __restrict__ h_out, float* __restrict__ x_out)
{
    const int l    = blockIdx.x & 7;
    const int i0   = (blockIdx.x >> 3) * IT;
    const int t    = threadIdx.x;
    const int lane = t & 63;
    const int w    = t >> 6;
    const int m    = lane & 15;
    const int quad = lane >> 4;

    __shared__ alignas(16) short al[IT][ABP];
    __shared__ float wmax[4][IT];
    __shared__ float wsum[4][IT];
    __shared__ float part3[4][IT][16];
    __shared__ float smS[IT][16];

    const bf16x8 aq0 = *(const bf16x8*)&q_ws[((size_t)l * NN + i0 + m) * 64 + quad * 8];
    const bf16x8 aq1 = *(const bf16x8*)&q_ws[((size_t)l * NN + i0 + m) * 64 + 32 + quad * 8];

    // ---- Phase 1: scores into REGISTERS; wave w covers j in [192w, 192w+192)
    f32x4 dsc[12];
    {
        const short* kl = k_ws + (size_t)l * NN * 64;
        #pragma unroll
        for (int nt = 0; nt < 12; ++nt) {
            const int jb = 192 * w + nt * 16;
            const short* krow = kl + (size_t)(jb + m) * 64;
            bf16x8 b0 = *(const bf16x8*)(krow + quad * 8);
            bf16x8 b1 = *(const bf16x8*)(krow + 32 + quad * 8);
            f32x4 d = {0.f, 0.f, 0.f, 0.f};
            d = __builtin_amdgcn_mfma_f32_16x16x32_bf16(aq0, b0, d, 0, 0, 0);
            d = __builtin_amdgcn_mfma_f32_16x16x32_bf16(aq1, b1, d, 0, 0, 0);
            dsc[nt] = d;
        }
    }

    // wave-local row max: in-lane over nt, then shfl over the 16 m-lanes
    float mx[4];
    #pragma unroll
    for (int rg = 0; rg < 4; ++rg) {
        float mm = dsc[0][rg];
        #pragma unroll
        for (int nt = 1; nt < 12; ++nt) mm = fmaxf(mm, dsc[nt][rg]);
        mm = fmaxf(mm, __shfl_xor(mm, 1, 64));
        mm = fmaxf(mm, __shfl_xor(mm, 2, 64));
        mm = fmaxf(mm, __shfl_xor(mm, 4, 64));
        mm = fmaxf(mm, __shfl_xor(mm, 8, 64));
        if (m == 0) wmax[w][quad * 4 + rg] = mm;
    }
    __syncthreads();
    #pragma unroll
    for (int rg = 0; rg < 4; ++rg) {
        const int row = quad * 4 + rg;
        mx[rg] = fmaxf(fmaxf(wmax[0][row], wmax[1][row]),
                       fmaxf(wmax[2][row], wmax[3][row]));
    }

    // exp from regs -> bf16 alpha in LDS; wave-local row sums
    float sl[4] = {0.f, 0.f, 0.f, 0.f};
    #pragma unroll
    for (int nt = 0; nt < 12; ++nt) {
        const int jb = 192 * w + nt * 16;
        #pragma unroll
        for (int rg = 0; rg < 4; ++rg) {
            const float e = __expf(dsc[nt][rg] - mx[rg]);
            sl[rg] += e;
            al[quad * 4 + rg][jb + m] = f2bf(e);
        }
    }
    #pragma unroll
    for (int rg = 0; rg < 4; ++rg) {
        float s = sl[rg];
        s += __shfl_xor(s, 1, 64);
        s += __shfl_xor(s, 2, 64);
        s += __shfl_xor(s, 4, 64);
        s += __shfl_xor(s, 8, 64);
        if (m == 0) wsum[w][quad * 4 + rg] = s;
    }
    __syncthreads();

    // ---- Phase 2: h_agg = alpha @ v; wave w owns c-tile [16w, 16w+16)
    {
        f32x4 acc0 = {0.f, 0.f, 0.f, 0.f};
        f32x4 acc1 = {0.f, 0.f, 0.f, 0.f};
        const short* vrow = vT_ws + ((size_t)l * 64 + 16 * w + m) * NN;
        #pragma unroll 4
        for (int kt = 0; kt < 24; kt += 2) {
            const int ka = kt * 32, kb = ka + 32;
            bf16x8 a0 = *(const bf16x8*)&al[m][ka + quad * 8];
            bf16x8 b0 = *(const bf16x8*)(vrow + ka + quad * 8);
            bf16x8 a1 = *(const bf16x8*)&al[m][kb + quad * 8];
            bf16x8 b1 = *(const bf16x8*)(vrow + kb + quad * 8);
            acc0 = __builtin_amdgcn_mfma_f32_16x16x32_bf16(a0, b0, acc0, 0, 0, 0);
            acc1 = __builtin_amdgcn_mfma_f32_16x16x32_bf16(a1, b1, acc1, 0, 0, 0);
        }
        const int c = 16 * w + m;
        #pragma unroll
        for (int rg = 0; rg < 4; ++rg) {
            const int i = quad * 4 + rg;
            const float ri = 1.f / (wsum[0][i] + wsum[1][i] +
                                    wsum[2][i] + wsum[3][i]);
            const int row = ((i0 + i) * 8 + l) * 64 + c;
            h_out[row] = h[row] + ri * (acc0[rg] + acc1[rg]);
        }
    }

    // ---- Phase 3: S = alpha @ U, 4-way K-split across waves
    {
        f32x4 acc = {0.f, 0.f, 0.f, 0.f};
        const short* urow = UT_ws + ((size_t)l * 16 + m) * NN + 192 * w;
        #pragma unroll
        for (int kt = 0; kt < 6; ++kt) {
            const int k0 = kt * 32;
            bf16x8 a = *(const bf16x8*)&al[m][192 * w + k0 + quad * 8];
            bf16x8 b = *(const bf16x8*)(urow + k0 + quad * 8);
            acc = __builtin_amdgcn_mfma_f32_16x16x32_bf16(a, b, acc, 0, 0, 0);
        }
        #pragma unroll
        for (int rg = 0; rg < 4; ++rg)
            part3[w][quad * 4 + rg][m] = acc[rg];
    }
    __syncthreads();
    {
        const int i = t >> 4, u = t & 15;
        const float ri = 1.f / (wsum[0][i] + wsum[1][i] +
                                wsum[2][i] + wsum[3][i]);
        smS[i][u] = (part3[0][i][u] + part3[1][i][u] +
                     part3[2][i][u] + part3[3][i][u]) * ri;
    }
    __syncthreads();
    if (t < 192) {
        const int i4 = t / 12, kt = t % 12, k4 = kt / 3, s4 = kt % 3;
        const int idx = ((i0 + i4) * 8 + l) * 12 + kt;
        const float cd = coord[idx];
        x_out[idx] = cd + cd * smS[i4][k4 * 4] - smS[i4][k4 * 4 + 1 + s4];
    }
}

extern "C" void kernel_launch(void* const* d_in, const int* in_sizes, int n_in,
                              void* d_out, int out_size, void* d_ws, size_t ws_size,
                              hipStream_t stream) {
    const float* h     = (const float*)d_in[0];
    const float* coord = (const float*)d_in[1];

    float* h_out = (float*)d_out;
    float* x_out = h_out + NN * LL * HH;     // 393216 floats

    short* q_ws  = (short*)d_ws;             // [L][N][64] bf16
    short* k_ws  = q_ws + NN * LL * HH;      // [L][N][64] bf16
    short* vT_ws = k_ws + NN * LL * HH;      // [L][64][N] bf16
    short* UT_ws = vT_ws + NN * LL * HH;     // [L][16][N] bf16
    short* WT    = UT_ws + NN * LL * 16;     // 29696 shorts of bf16 weights

    prep_kernel<<<116, 256, 0, stream>>>(
        (const float*)d_in[2],  (const float*)d_in[4],
        (const float*)d_in[6],  (const float*)d_in[8],
        (const float*)d_in[10], (const float*)d_in[12],
        (const float*)d_in[14], (const float*)d_in[16], WT);

    qkv_kernel<<<288, 256, 0, stream>>>(
        h, coord,
        (const float*)d_in[3],  (const float*)d_in[5],
        (const float*)d_in[7],  (const float*)d_in[9],
        (const float*)d_in[11], (const float*)d_in[13],
        (const float*)d_in[15],
        WT, q_ws, k_ws, vT_ws, UT_ws);

    attn_kernel<<<(NN / IT) * LL, 256, 0, stream>>>(
        q_ws, k_ws, vT_ws, UT_ws, h, coord, h_out, x_out);
}

// Round 17
// 112.012 us; speedup vs baseline: 1.0946x; 1.0215x over previous
//
#include <hip/hip_runtime.h>
#include <hip/hip_bf16.h>

#define NN 768
#define LL 8
#define HH 64
#define IT 16     // attn i-tile
#define ABP 776   // bf16 alpha row stride (shorts); 1552 B, 16B-aligned
#define XST 80    // qkv LDS X-tile row stride in shorts (160 B, 16B-aligned)

typedef __attribute__((ext_vector_type(8))) short bf16x8;
typedef __attribute__((ext_vector_type(4))) float f32x4;

__device__ __forceinline__ short f2bf(float x) {
    union { __hip_bfloat16 h; short s; } u;
    u.h = __float2bfloat16(x);
    return u.s;
}

__device__ __forceinline__ bf16x8 pack8(float4 lo, float4 hi) {
    bf16x8 r;
    r[0] = f2bf(lo.x); r[1] = f2bf(lo.y); r[2] = f2bf(lo.z); r[3] = f2bf(lo.w);
    r[4] = f2bf(hi.x); r[5] = f2bf(hi.y); r[6] = f2bf(hi.z); r[7] = f2bf(hi.w);
    return r;
}

// One 64->64 MFMA layer for a 16-row tile held by ONE wave.
// B-frags built directly from fp32 k-major W (no prep kernel): for col
// n = nt*16+m, b[j] = bf16(W[(khalf*32 + quad*8 + j)*64 + n]). Same f2bf
// rounding as the old prep path -> bit-identical results.
__device__ __forceinline__ void layer_mfma(bf16x8 a0, bf16x8 a1,
                                           const float* __restrict__ W,
                                           const float* __restrict__ bias,
                                           int m, int quad, bool do_relu,
                                           f32x4 dout[4])
{
    #pragma unroll
    for (int nt = 0; nt < 4; ++nt) {
        const int n = nt * 16 + m;
        const float* wp = W + (quad * 8) * 64 + n;
        bf16x8 b0, b1;
        #pragma unroll
        for (int j = 0; j < 8; ++j) b0[j] = f2bf(wp[j * 64]);
        #pragma unroll
        for (int j = 0; j < 8; ++j) b1[j] = f2bf(wp[(32 + j) * 64]);
        f32x4 d = {0.f, 0.f, 0.f, 0.f};
        d = __builtin_amdgcn_mfma_f32_16x16x32_bf16(a0, b0, d, 0, 0, 0);
        d = __builtin_amdgcn_mfma_f32_16x16x32_bf16(a1, b1, d, 0, 0, 0);
        if (bias) {
            const float bb = bias[n];
            #pragma unroll
            for (int rg = 0; rg < 4; ++rg) d[rg] += bb;
        }
        if (do_relu) {
            #pragma unroll
            for (int rg = 0; rg < 4; ++rg) d[rg] = fmaxf(d[rg], 0.f);
        }
        dout[nt] = d;
    }
}

__device__ __forceinline__ void d_to_X(const f32x4 d[4], short (*X)[XST],
                                       int m, int quad) {
    #pragma unroll
    for (int nt = 0; nt < 4; ++nt)
        #pragma unroll
        for (int rg = 0; rg < 4; ++rg)
            X[quad * 4 + rg][nt * 16 + m] = f2bf(d[nt][rg]);
}

// Kernel 1 v9: MFMA MLPs with direct-W fragment loads (prep kernel folded in).
// wave-task = (16-row tile, chain). 384 tiles x 3 chains = 1152 waves.
__global__ __launch_bounds__(256) void qkv_kernel(
    const float* __restrict__ h, const float* __restrict__ coord,
    const float* __restrict__ wq1, const float* __restrict__ bq1,
    const float* __restrict__ wq2, const float* __restrict__ bq2,
    const float* __restrict__ wk1, const float* __restrict__ bk1,
    const float* __restrict__ wk2, const float* __restrict__ bk2,
    const float* __restrict__ wv1, const float* __restrict__ bv1,
    const float* __restrict__ wv2, const float* __restrict__ bv2,
    const float* __restrict__ wc1, const float* __restrict__ bc1,
    const float* __restrict__ wc2,
    short* __restrict__ q_ws, short* __restrict__ k_ws,
    short* __restrict__ vT_ws, short* __restrict__ UT_ws)
{
    const int lane = threadIdx.x & 63;
    const int w    = threadIdx.x >> 6;
    const int wid  = blockIdx.x * 4 + w;
    const int chain = wid / 384;           // 0=q 1=k 2=v+cmv
    const int rt    = wid - chain * 384;   // 16-row tile
    const int r0    = rt * 16;

    const int m    = lane & 15;
    const int quad = lane >> 4;

    __shared__ short Xs[4][16][XST];
    __shared__ float cms[4][16][4];
    short (*X)[XST] = Xs[w];

    // layer-1 A-frags straight from global h (fp32 -> bf16)
    bf16x8 a0, a1;
    {
        const float* hrow = h + (size_t)(r0 + m) * 64;
        a0 = pack8(*(const float4*)(hrow + quad * 8),
                   *(const float4*)(hrow + quad * 8 + 4));
        a1 = pack8(*(const float4*)(hrow + 32 + quad * 8),
                   *(const float4*)(hrow + 32 + quad * 8 + 4));
    }

    f32x4 d[4];

    if (chain == 0) {
        layer_mfma(a0, a1, wq1, bq1, m, quad, true, d);
        d_to_X(d, X, m, quad);
        __builtin_amdgcn_wave_barrier();
        a0 = *(const bf16x8*)&X[m][quad * 8];
        a1 = *(const bf16x8*)&X[m][32 + quad * 8];
        layer_mfma(a0, a1, wq2, bq2, m, quad, true, d);
        #pragma unroll
        for (int nt = 0; nt < 4; ++nt)
            #pragma unroll
            for (int rg = 0; rg < 4; ++rg) {
                const int g = r0 + quad * 4 + rg, i = g >> 3, l = g & 7;
                q_ws[(l * NN + i) * 64 + nt * 16 + m] = f2bf(d[nt][rg]);
            }
    } else if (chain == 1) {
        layer_mfma(a0, a1, wk1, bk1, m, quad, true, d);
        d_to_X(d, X, m, quad);
        __builtin_amdgcn_wave_barrier();
        a0 = *(const bf16x8*)&X[m][quad * 8];
        a1 = *(const bf16x8*)&X[m][32 + quad * 8];
        layer_mfma(a0, a1, wk2, bk2, m, quad, true, d);
        #pragma unroll
        for (int nt = 0; nt < 4; ++nt)
            #pragma unroll
            for (int rg = 0; rg < 4; ++rg) {
                const int g = r0 + quad * 4 + rg, i = g >> 3, l = g & 7;
                k_ws[(l * NN + i) * 64 + nt * 16 + m] = f2bf(d[nt][rg]);
            }
    } else {
        layer_mfma(a0, a1, wv1, bv1, m, quad, true, d);
        d_to_X(d, X, m, quad);
        __builtin_amdgcn_wave_barrier();
        a0 = *(const bf16x8*)&X[m][quad * 8];
        a1 = *(const bf16x8*)&X[m][32 + quad * 8];
        layer_mfma(a0, a1, wv2, bv2, m, quad, true, d);
        // v: transposed stores + back into X (input to coord_mlp)
        #pragma unroll
        for (int nt = 0; nt < 4; ++nt)
            #pragma unroll
            for (int rg = 0; rg < 4; ++rg) {
                const int g = r0 + quad * 4 + rg, i = g >> 3, l = g & 7;
                vT_ws[((size_t)l * 64 + nt * 16 + m) * NN + i] = f2bf(d[nt][rg]);
            }
        d_to_X(d, X, m, quad);
        __builtin_amdgcn_wave_barrier();
        a0 = *(const bf16x8*)&X[m][quad * 8];
        a1 = *(const bf16x8*)&X[m][32 + quad * 8];
        layer_mfma(a0, a1, wc1, bc1, m, quad, true, d);
        d_to_X(d, X, m, quad);
        __builtin_amdgcn_wave_barrier();
        a0 = *(const bf16x8*)&X[m][quad * 8];
        a1 = *(const bf16x8*)&X[m][32 + quad * 8];
        // cmv = t1 @ wc2 (no bias/relu); wc2 is [64][4], cols m>=4 are zero
        {
            bf16x8 b0, b1;
            #pragma unroll
            for (int j = 0; j < 8; ++j) {
                b0[j] = (m < 4) ? f2bf(wc2[(quad * 8 + j) * 4 + m]) : (short)0;
                b1[j] = (m < 4) ? f2bf(wc2[(32 + quad * 8 + j) * 4 + m]) : (short)0;
            }
            f32x4 dc = {0.f, 0.f, 0.f, 0.f};
            dc = __builtin_amdgcn_mfma_f32_16x16x32_bf16(a0, b0, dc, 0, 0, 0);
            dc = __builtin_amdgcn_mfma_f32_16x16x32_bf16(a1, b1, dc, 0, 0, 0);
            if (m < 4) {
                #pragma unroll
                for (int rg = 0; rg < 4; ++rg)
                    cms[w][quad * 4 + rg][m] = dc[rg];
            }
        }
        __builtin_amdgcn_wave_barrier();
        // U build: lane -> (row = lane>>2, kk = lane&3), 4 seg outputs
        {
            const int row = lane >> 2, kk = lane & 3;
            const float c = cms[w][row][kk];
            const int g = r0 + row, i = g >> 3, l = g & 7;
            UT_ws[((size_t)l * 16 + kk * 4 + 0) * NN + i] = f2bf(c);
            #pragma unroll
            for (int seg = 1; seg < 4; ++seg) {
                const float uval = c * coord[g * 12 + kk * 3 + (seg - 1)];
                UT_ws[((size_t)l * 16 + kk * 4 + seg) * NN + i] = f2bf(uval);
            }
        }
    }
}

// Kernel 2 v7 (frozen from R16): register-resident scores, ~31KB LDS.
__global__ __launch_bounds__(256) void attn_kernel(
    const short* __restrict__ q_ws, const short* __restrict__ k_ws,
    const short* __restrict__ vT_ws, const short* __restrict__ UT_ws,
    const float* __restrict__ h, const float* __restrict__ coord,
    float* __restrict__ h_out, float* __restrict__ x_out)
{
    const int l    = blockIdx.x & 7;
    const int i0   = (blockIdx.x >> 3) * IT;
    const int t    = threadIdx.x;
    const int lane = t & 63;
    const int w    = t >> 6;
    const int m    = lane & 15;
    const int quad = lane >> 4;

    __shared__ alignas(16) short al[IT][ABP];
    __shared__ float wmax[4][IT];
    __shared__ float wsum[4][IT];
    __shared__ float part3[4][IT][16];
    __shared__ float smS[IT][16];

    const bf16x8 aq0 = *(const bf16x8*)&q_ws[((size_t)l * NN + i0 + m) * 64 + quad * 8];
    const bf16x8 aq1 = *(const bf16x8*)&q_ws[((size_t)l * NN + i0 + m) * 64 + 32 + quad * 8];

    f32x4 dsc[12];
    {
        const short* kl = k_ws + (size_t)l * NN * 64;
        #pragma unroll
        for (int nt = 0; nt < 12; ++nt) {
            const int jb = 192 * w + nt * 16;
            const short* krow = kl + (size_t)(jb + m) * 64;
            bf16x8 b0 = *(const bf16x8*)(krow + quad * 8);
            bf16x8 b1 = *(const bf16x8*)(krow + 32 + quad * 8);
            f32x4 d = {0.f, 0.f, 0.f, 0.f};
            d = __builtin_amdgcn_mfma_f32_16x16x32_bf16(aq0, b0, d, 0, 0, 0);
            d = __builtin_amdgcn_mfma_f32_16x16x32_bf16(aq1, b1, d, 0, 0, 0);
            dsc[nt] = d;
        }
    }

    float mx[4];
    #pragma unroll
    for (int rg = 0; rg < 4; ++rg) {
        float mm = dsc[0][rg];
        #pragma unroll
        for (int nt = 1; nt < 12; ++nt) mm = fmaxf(mm, dsc[nt][rg]);
        mm = fmaxf(mm, __shfl_xor(mm, 1, 64));
        mm = fmaxf(mm, __shfl_xor(mm, 2, 64));
        mm = fmaxf(mm, __shfl_xor(mm, 4, 64));
        mm = fmaxf(mm, __shfl_xor(mm, 8, 64));
        if (m == 0) wmax[w][quad * 4 + rg] = mm;
    }
    __syncthreads();
    #pragma unroll
    for (int rg = 0; rg < 4; ++rg) {
        const int row = quad * 4 + rg;
        mx[rg] = fmaxf(fmaxf(wmax[0][row], wmax[1][row]),
                       fmaxf(wmax[2][row], wmax[3][row]));
    }

    float sl[4] = {0.f, 0.f, 0.f, 0.f};
    #pragma unroll
    for (int nt = 0; nt < 12; ++nt) {
        const int jb = 192 * w + nt * 16;
        #pragma unroll
        for (int rg = 0; rg < 4; ++rg) {
            const float e = __expf(dsc[nt][rg] - mx[rg]);
            sl[rg] += e;
            al[quad * 4 + rg][jb + m] = f2bf(e);
        }
    }
    #pragma unroll
    for (int rg = 0; rg < 4; ++rg) {
        float s = sl[rg];
        s += __shfl_xor(s, 1, 64);
        s += __shfl_xor(s, 2, 64);
        s += __shfl_xor(s, 4, 64);
        s += __shfl_xor(s, 8, 64);
        if (m == 0) wsum[w][quad * 4 + rg] = s;
    }
    __syncthreads();

    {
        f32x4 acc0 = {0.f, 0.f, 0.f, 0.f};
        f32x4 acc1 = {0.f, 0.f, 0.f, 0.f};
        const short* vrow = vT_ws + ((size_t)l * 64 + 16 * w + m) * NN;
        #pragma unroll 4
        for (int kt = 0; kt < 24; kt += 2) {
            const int ka = kt * 32, kb = ka + 32;
            bf16x8 a0 = *(const bf16x8*)&al[m][ka + quad * 8];
            bf16x8 b0 = *(const bf16x8*)(vrow + ka + quad * 8);
            bf16x8 a1 = *(const bf16x8*)&al[m][kb + quad * 8];
            bf16x8 b1 = *(const bf16x8*)(vrow + kb + quad * 8);
            acc0 = __builtin_amdgcn_mfma_f32_16x16x32_bf16(a0, b0, acc0, 0, 0, 0);
            acc1 = __builtin_amdgcn_mfma_f32_16x16x32_bf16(a1, b1, acc1, 0, 0, 0);
        }
        const int c = 16 * w + m;
        #pragma unroll
        for (int rg = 0; rg < 4; ++rg) {
            const int i = quad * 4 + rg;
            const float ri = 1.f / (wsum[0][i] + wsum[1][i] +
                                    wsum[2][i] + wsum[3][i]);
            const int row = ((i0 + i) * 8 + l) * 64 + c;
            h_out[row] = h[row] + ri * (acc0[rg] + acc1[rg]);
        }
    }

    {
        f32x4 acc = {0.f, 0.f, 0.f, 0.f};
        const short* urow = UT_ws + ((size_t)l * 16 + m) * NN + 192 * w;
        #pragma unroll
        for (int kt = 0; kt < 6; ++kt) {
            const int k0 = kt * 32;
            bf16x8 a = *(const bf16x8*)&al[m][192 * w + k0 + quad * 8];
            bf16x8 b = *(const bf16x8*)(urow + k0 + quad * 8);
            acc = __builtin_amdgcn_mfma_f32_16x16x32_bf16(a, b, acc, 0, 0, 0);
        }
        #pragma unroll
        for (int rg = 0; rg < 4; ++rg)
            part3[w][quad * 4 + rg][m] = acc[rg];
    }
    __syncthreads();
    {
        const int i = t >> 4, u = t & 15;
        const float ri = 1.f / (wsum[0][i] + wsum[1][i] +
                                wsum[2][i] + wsum[3][i]);
        smS[i][u] = (part3[0][i][u] + part3[1][i][u] +
                     part3[2][i][u] + part3[3][i][u]) * ri;
    }
    __syncthreads();
    if (t < 192) {
        const int i4 = t / 12, kt = t % 12, k4 = kt / 3, s4 = kt % 3;
        const int idx = ((i0 + i4) * 8 + l) * 12 + kt;
        const float cd = coord[idx];
        x_out[idx] = cd + cd * smS[i4][k4 * 4] - smS[i4][k4 * 4 + 1 + s4];
    }
}

extern "C" void kernel_launch(void* const* d_in, const int* in_sizes, int n_in,
                              void* d_out, int out_size, void* d_ws, size_t ws_size,
                              hipStream_t stream) {
    const float* h     = (const float*)d_in[0];
    const float* coord = (const float*)d_in[1];

    float* h_out = (float*)d_out;
    float* x_out = h_out + NN * LL * HH;     // 393216 floats

    short* q_ws  = (short*)d_ws;             // [L][N][64] bf16
    short* k_ws  = q_ws + NN * LL * HH;      // [L][N][64] bf16
    short* vT_ws = k_ws + NN * LL * HH;      // [L][64][N] bf16
    short* UT_ws = vT_ws + NN * LL * HH;     // [L][16][N] bf16

    qkv_kernel<<<288, 256, 0, stream>>>(
        h, coord,
        (const float*)d_in[2],  (const float*)d_in[3],
        (const float*)d_in[4],  (const float*)d_in[5],
        (const float*)d_in[6],  (const float*)d_in[7],
        (const float*)d_in[8],  (const float*)d_in[9],
        (const float*)d_in[10], (const float*)d_in[11],
        (const float*)d_in[12], (const float*)d_in[13],
        (const float*)d_in[14], (const float*)d_in[15],
        (const float*)d_in[16],
        q_ws, k_ws, vT_ws, UT_ws);

    attn_kernel<<<(NN / IT) * LL, 256, 0, stream>>>(
        q_ws, k_ws, vT_ws, UT_ws, h, coord, h_out, x_out);
}